// Round 8
// baseline (22600.592 us; speedup 1.0000x reference)
//
#include <hip/hip_runtime.h>
#include <math.h>

// SynchronGRU R14: 2 blocks/CU TLP — fill the barrier/gate idle.
// R13 (2.79 ms rocprof) = ~3270 cy/step vs ~1250 cy modeled critical path:
// two barriers/step + a gate phase where only 4/12 waves work leave ~half
// the step idle, and at 1 block/CU (Occupancy 36%) nothing fills the gap.
// R14: kRows 2 -> 1. 512 blocks, 2 blocks/CU (LDS 82->43 KB, 24 waves/CU).
// The two co-resident blocks are independent recurrences: one block's
// h-dot overlaps the other's gate/barrier phase. Total work unchanged.
// __launch_bounds__(768,6) pins VGPR<=85 (R13 fit 84 with MORE live state:
// half the accumulators/C-tiles here). Health check: FETCH must stay
// ~247 MB; GBs = scratch spill relapse (R10 failure mode).
// Everything else is the kRows=1 specialization of R13 (MFMA x-GEMM with
// per-lane global B-frags, bf16x3; fp32 register-resident h-dot).

namespace {

constexpr int kB = 512;
constexpr int kT = 256;
constexpr int kF = 8;
constexpr int kU = 128;
constexpr int kG = 384;   // 3*U, gate order [z, r, h]
constexpr int kL = 8;
constexpr int kThreads = 768;  // 12 waves; 2 blocks/CU -> 6 waves/SIMD
constexpr int kSt = 16;        // time-steps per chunk (x-GEMM M = 16)
constexpr int kXRow = 132;     // padded xstage row stride (floats)

// LDS layout (floats), per block (~43 KB -> 2 blocks/CU)
constexpr int kOffXstage = 0;                      // [16][132] = 2112
constexpr int kOffXg     = 2112;                   // [16][384] = 6144
constexpr int kOffHbuf   = 2112 + 6144;            // [128]        (8256)
constexpr int kOffPacc   = kOffHbuf + 128;         // [4kq][384] = 1536 (8384)
constexpr int kOffCinit  = kOffPacc + 1536;        // [384] (9920)
constexpr int kOffBiash  = kOffCinit + 384;        // [384] (10304)
constexpr int kSmemFloats = kOffBiash + 384;       // 10688 floats = 42.75 KB
static_assert(kSmemFloats * 4 * 2 <= 160 * 1024, "2 blocks/CU LDS budget");

typedef __attribute__((ext_vector_type(8))) short short8;
typedef __attribute__((ext_vector_type(4))) float f32x4;

__device__ __forceinline__ float frcp(float x) { return __builtin_amdgcn_rcpf(x); }

// split 8 fp32 (two float4, consecutive k) into bf16-hi / bf16-lo fragments
__device__ __forceinline__ void split8(const float4 a, const float4 b,
                                       short8& hi, short8& lo) {
    union { unsigned u[4]; short8 v; } H, L;
    const float f[8] = {a.x, a.y, a.z, a.w, b.x, b.y, b.z, b.w};
#pragma unroll
    for (int i = 0; i < 4; ++i) {
        const unsigned u0 = __float_as_uint(f[2 * i]);
        const unsigned u1 = __float_as_uint(f[2 * i + 1]);
        H.u[i] = (u0 >> 16) | (u1 & 0xFFFF0000u);
        const float r0 = f[2 * i]     - __uint_as_float(u0 & 0xFFFF0000u);
        const float r1 = f[2 * i + 1] - __uint_as_float(u1 & 0xFFFF0000u);
        L.u[i] = (__float_as_uint(r0) >> 16) | (__float_as_uint(r1) & 0xFFFF0000u);
    }
    hi = H.v; lo = L.v;
}

// pack 8 scalars (statically unrolled) into bf16 hi/lo fragments
__device__ __forceinline__ void pack8(const float* f, short8& hi, short8& lo) {
    union { unsigned u[4]; short8 v; } H, L;
#pragma unroll
    for (int i = 0; i < 4; ++i) {
        const unsigned u0 = __float_as_uint(f[2 * i]);
        const unsigned u1 = __float_as_uint(f[2 * i + 1]);
        H.u[i] = (u0 >> 16) | (u1 & 0xFFFF0000u);
        const float r0 = f[2 * i]     - __uint_as_float(u0 & 0xFFFF0000u);
        const float r1 = f[2 * i + 1] - __uint_as_float(u1 & 0xFFFF0000u);
        L.u[i] = (__float_as_uint(r0) >> 16) | (__float_as_uint(r1) & 0xFFFF0000u);
    }
    hi = H.v; lo = L.v;
}

#define MFMA3(C, Ahi, Alo, Bhi, Blo)                                          \
    C = __builtin_amdgcn_mfma_f32_16x16x32_bf16((Ahi), (Bhi), C, 0, 0, 0);    \
    C = __builtin_amdgcn_mfma_f32_16x16x32_bf16((Ahi), (Blo), C, 0, 0, 0);    \
    C = __builtin_amdgcn_mfma_f32_16x16x32_bf16((Alo), (Bhi), C, 0, 0, 0);

__global__ __launch_bounds__(kThreads, 6) void gru_all(
    const float* __restrict__ xin,      // (B,T,F)
    const float* __restrict__ init_h,   // (L,B,U)
    const float* __restrict__ kernel0,  // (F,3U)
    const float* __restrict__ kernels,  // (L-1,U,3U)
    const float* __restrict__ rec_k,    // (L,U,3U)
    const float* __restrict__ biases,   // (L,2,3U)
    float* __restrict__ out)            // (B,T,U) seq out | (L,B,U) states
{
    __shared__ __align__(16) float smem[kSmemFloats];
    float* xstage = smem + kOffXstage;
    float* xg     = smem + kOffXg;
    float* hbuf   = smem + kOffHbuf;
    float* pacc   = smem + kOffPacc;
    float* cinit  = smem + kOffCinit;
    float* biash  = smem + kOffBiash;

    const int tid  = threadIdx.x;
    const int b0   = blockIdx.x;          // ONE batch row per block
    const int lane = tid & 63;
    const int wv   = tid >> 6;
    const int ln15 = lane & 15;
    const int lh   = lane >> 4;
    // h-dot identity: wave-uniform k-quarter, cols {ch, 192+ch}
    const int kq = wv & 3;
    const int ch = ((wv >> 2) << 6) + lane;  // 0..191
    // x-MFMA identity: wave owns N-tiles {2wv, 2wv+1}
    const int ntA = 2 * wv, ntB = 2 * wv + 1;

    float* __restrict__ buf    = out;                        // in-place activations
    float* __restrict__ states = out + (size_t)kB * kT * kU; // final h per layer

    // zero xstage once: layer 0 writes only k 0..7; rest must be 0.
    for (int j = tid; j < kSt * kXRow; j += kThreads) xstage[j] = 0.f;

#pragma unroll 1
    for (int l = 0; l < kL; ++l) {
        // ---- W_h -> registers (once per layer): 64 floats/thread ----
        float whA[32], whB[32];
        {
            const float* Wh = rec_k + (size_t)l * kU * kG;
#pragma unroll
            for (int i = 0; i < 32; ++i) {
                const float* p = Wh + (size_t)(32 * kq + i) * kG;
                whA[i] = p[ch]; whB[i] = p[192 + ch];
            }
        }
        // biases: cinit = biasx + (col<256 ? biash : 0) folded into MFMA C-init
        if (tid < kG) {
            const float bx = biases[(size_t)l * 2 * kG + tid];
            const float bh = biases[(size_t)l * 2 * kG + kG + tid];
            cinit[tid] = bx + (tid < 2 * kU ? bh : 0.f);
            biash[tid] = bh;
        }
        if (tid < kU)
            hbuf[tid] = init_h[(size_t)l * kB * kU + (size_t)b0 * kU + tid];
        __syncthreads();

        const int nkt = (l == 0) ? 1 : 4;  // 32-k tiles (l0: K=8, zero-padded)

#pragma unroll 1
        for (int t0 = 0; t0 < kT; t0 += kSt) {
            // ---- X1: stage x for the next 16 steps (padded rows) ----
            if (l == 0) {
                if (tid < 32) {
                    const int tt = tid >> 1, hf = tid & 1;
                    *(float4*)&xstage[tt * kXRow + 4 * hf] =
                        *(const float4*)(xin + ((size_t)b0 * kT + (t0 + tt)) * kF + 4 * hf);
                }
            } else {
                if (tid < 512) {
                    const int tt = tid >> 5, c4 = tid & 31;
                    *(float4*)&xstage[tt * kXRow + 4 * c4] =
                        *(const float4*)(buf + ((size_t)b0 * kT + (t0 + tt)) * kU + 4 * c4);
                }
            }
            __syncthreads();

            // ---- X2: x-GEMM via MFMA (M=16); B frags per-lane from global ----
            {
                const float ciA = cinit[ntA * 16 + ln15];
                const float ciB = cinit[ntB * 16 + ln15];
                f32x4 C00 = {ciA, ciA, ciA, ciA};  // [ntA]
                f32x4 C01 = {ciB, ciB, ciB, ciB};  // [ntB]

                const float* Wxp = (l == 0) ? kernel0
                                            : kernels + (size_t)(l - 1) * kU * kG;
                asm volatile("" : "+v"(Wxp));  // no LICM hoist across t0 loop

#pragma unroll 1
                for (int kt = 0; kt < nkt; ++kt) {
                    // B fragments: lane loads its 8 weights (col = nt*16+ln15,
                    // k = kt*32 + lh*8 + eo); 16-lane groups -> coalesced 64B.
                    float fA[8], fB[8];
#pragma unroll
                    for (int eo = 0; eo < 8; ++eo) {
                        const int row = kt * 32 + lh * 8 + eo;
                        float vA = 0.f, vB = 0.f;
                        if (l != 0 || row < kF) {
                            const float* rp = Wxp + (size_t)row * kG;
                            vA = rp[ntA * 16 + ln15];
                            vB = rp[ntB * 16 + ln15];
                        }
                        fA[eo] = vA; fB[eo] = vB;
                    }
                    short8 BhiA, BloA, BhiB, BloB;
                    pack8(fA, BhiA, BloA);
                    pack8(fB, BhiB, BloB);

                    // A-fragment from xstage (M-row = ln15 -> step tt,
                    // k = kt*32 + lh*8 + e)
                    const float4* xs4 = (const float4*)xstage;
                    const int fi0 = ln15 * (kXRow / 4) + kt * 8 + lh * 2;
                    short8 Ahi0, Alo0;
                    split8(xs4[fi0], xs4[fi0 + 1], Ahi0, Alo0);

                    MFMA3(C00, Ahi0, Alo0, BhiA, BloA)
                    MFMA3(C01, Ahi0, Alo0, BhiB, BloB)
                }

                // write xg: D row = (lh*4 + reg) -> step tt
#pragma unroll
                for (int reg = 0; reg < 4; ++reg) {
                    const int ml = lh * 4 + reg;
                    xg[ml * kG + ntA * 16 + ln15] = C00[reg];
                    xg[ml * kG + ntB * 16 + ln15] = C01[reg];
                }
            }
            __syncthreads();

            // ---- 16 recurrence steps: register W_h + LDS broadcasts ----
#pragma unroll 1
            for (int tt = 0; tt < kSt; ++tt) {
                {
                    const float4* hs0 = (const float4*)&hbuf[32 * kq];
                    float a0A = 0.f, a0B = 0.f;
#pragma unroll
                    for (int k4 = 0; k4 < 8; ++k4) {
                        const float4 h0 = hs0[k4];
                        a0A += whA[4 * k4 + 0] * h0.x; a0B += whB[4 * k4 + 0] * h0.x;
                        a0A += whA[4 * k4 + 1] * h0.y; a0B += whB[4 * k4 + 1] * h0.y;
                        a0A += whA[4 * k4 + 2] * h0.z; a0B += whB[4 * k4 + 2] * h0.z;
                        a0A += whA[4 * k4 + 3] * h0.w; a0B += whB[4 * k4 + 3] * h0.w;
                    }
                    pacc[kq * kG + ch]       = a0A;
                    pacc[kq * kG + 192 + ch] = a0B;
                }
                __syncthreads();

                // ---- gates: threads 0..127 = unit; biases pre-folded ----
                if (tid < kU) {
                    const float* xgp = &xg[(size_t)tt * kG];
                    float sz = 0.f, sr = 0.f, sp = 0.f;
#pragma unroll
                    for (int k2 = 0; k2 < 4; ++k2) {
                        const float* ph = pacc + (size_t)k2 * kG;
                        sz += ph[tid]; sr += ph[kU + tid]; sp += ph[2 * kU + tid];
                    }
                    const float z  = frcp(1.f + __expf(-(xgp[tid] + sz)));
                    const float rg = frcp(1.f + __expf(-(xgp[kU + tid] + sr)));
                    const float ta = xgp[2 * kU + tid] + rg * (sp + biash[2 * kU + tid]);
                    const float hh = 1.f - 2.f * frcp(1.f + __expf(2.f * ta));  // tanh
                    const float h  = z * hbuf[tid] + (1.f - z) * hh;
                    hbuf[tid] = h;
                    buf[((size_t)b0 * kT + (t0 + tt)) * kU + tid] = h;
                }
                __syncthreads();
            }
        }

        // ---- final state of this layer ----
        if (tid < kU)
            states[(size_t)l * kB * kU + (size_t)b0 * kU + tid] = hbuf[tid];
        __syncthreads();
    }
}

}  // namespace

extern "C" void kernel_launch(void* const* d_in, const int* in_sizes, int n_in,
                              void* d_out, int out_size, void* d_ws, size_t ws_size,
                              hipStream_t stream) {
    const float* xin     = (const float*)d_in[0];
    const float* init_h  = (const float*)d_in[1];
    const float* kernel0 = (const float*)d_in[2];
    const float* kernels = (const float*)d_in[3];
    const float* rec_k   = (const float*)d_in[4];
    const float* biases  = (const float*)d_in[5];
    float* out = (float*)d_out;

    dim3 grid(kB);           // 512 blocks (1 batch row each) -> 2 blocks/CU
    dim3 block(kThreads);    // 768 threads = 12 waves; 6 waves/SIMD resident
    gru_all<<<grid, block, 0, stream>>>(xin, init_h, kernel0, kernels, rec_k, biases, out);
}

// Round 9
// 2901.983 us; speedup vs baseline: 7.7880x; 7.7880x over previous
//
#include <hip/hip_runtime.h>
#include <math.h>

// SynchronGRU R15: h-dot on the MFMA pipe; hi/lo parts ride the N dimension.
// R14 post-mortem: occupancy tiers quantize at VGPR 64/128/256. Demanding
// 6 waves/SIMD forced a 64-VGPR target -> RA dumped resident weights to
// scratch (VGPR 40, FETCH 55 GB, 22.6 ms). 2 blocks/CU is unreachable with
// 64 resident floats; revert to the R13 shell (1 blk/CU, bounds(768,3)).
// R13's wall: VALU 77% busy, h-dot issue 768 cy/SIMD/step on the VALU pipe
// while MfmaUtil sat at 4.5%. R15 moves the h-dot to MFMA despite M=2:
//   D[384 W-cols][n=(row,part)] = mfma(A=W-frag, B=h-frag), n packs
//   (r0hi, r0lo, r1hi, r1lo). Two MFMAs per (m-tile,k-frag): A=Whi over all
//   n, A=Wlo (only n=hi cols used). Gate sums D1[u][2r]+D1[u][2r+1]+D2[u][2r]
//   == Whi*hhi + Whi*hlo + Wlo*hhi (bf16x3 precision, same as the x-GEMM).
// W_h resident as pre-packed bf16 hi/lo fragments: 64 u32/thread (same
// budget as R13's 64 floats). h-frags rebuilt each step by gate threads into
// a 4 KB LDS buffer (XOR-swizzled 16B slots: s ^= ((s>>4)&3) ^ ((s>>6)&3)<<2
// spreads the b16 writes over all 8 bank-groups); MFMA lanes read 1 masked
// ds_read_b128 per k-frag (16 active lanes). 16 MFMA/wave/step (~230 cy/SIMD)
// replaces 768 cy of VALU FMA. X1/X2 (x-GEMM via MFMA) verbatim from R13.

namespace {

constexpr int kB = 512;
constexpr int kT = 256;
constexpr int kF = 8;
constexpr int kU = 128;
constexpr int kG = 384;   // 3*U, gate order [z, r, h]
constexpr int kL = 8;
constexpr int kRows = 2;       // batch rows per block
constexpr int kThreads = 768;  // 12 waves, 3 per SIMD (VGPR tier <=128)
constexpr int kSt = 16;        // time-steps per chunk (x-GEMM M = 32)
constexpr int kXRow = 132;     // padded xstage row stride (floats)

// LDS layout (floats)
constexpr int kOffXstage = 0;                  // [32][132] = 4224
constexpr int kOffXg     = 4224;               // [2r][16tt][384] = 12288
constexpr int kOffP1     = 16512;              // [4 n][388] = 1552 (Whi partials)
constexpr int kOffP2     = 18064;              // [2 r][388] = 776  (Wlo partials)
constexpr int kOffHfrag  = 18840;              // 256 slots x 16B = 1024 floats
constexpr int kOffCinit  = 19864;              // [384]
constexpr int kOffBiash  = 20248;              // [384]
constexpr int kSmemFloats = 20632;             // 82.5 KB -> 1 block/CU
static_assert(kSmemFloats * 4 <= 160 * 1024, "LDS budget");

typedef __attribute__((ext_vector_type(8))) short short8;
typedef __attribute__((ext_vector_type(4))) float f32x4;

__device__ __forceinline__ float frcp(float x) { return __builtin_amdgcn_rcpf(x); }

// split 8 fp32 (two float4, consecutive k) into bf16-hi / bf16-lo fragments
__device__ __forceinline__ void split8(const float4 a, const float4 b,
                                       short8& hi, short8& lo) {
    union { unsigned u[4]; short8 v; } H, L;
    const float f[8] = {a.x, a.y, a.z, a.w, b.x, b.y, b.z, b.w};
#pragma unroll
    for (int i = 0; i < 4; ++i) {
        const unsigned u0 = __float_as_uint(f[2 * i]);
        const unsigned u1 = __float_as_uint(f[2 * i + 1]);
        H.u[i] = (u0 >> 16) | (u1 & 0xFFFF0000u);
        const float r0 = f[2 * i]     - __uint_as_float(u0 & 0xFFFF0000u);
        const float r1 = f[2 * i + 1] - __uint_as_float(u1 & 0xFFFF0000u);
        L.u[i] = (__float_as_uint(r0) >> 16) | (__float_as_uint(r1) & 0xFFFF0000u);
    }
    hi = H.v; lo = L.v;
}

// pack 8 scalars (statically unrolled) into bf16 hi/lo fragments
__device__ __forceinline__ void pack8(const float* f, short8& hi, short8& lo) {
    union { unsigned u[4]; short8 v; } H, L;
#pragma unroll
    for (int i = 0; i < 4; ++i) {
        const unsigned u0 = __float_as_uint(f[2 * i]);
        const unsigned u1 = __float_as_uint(f[2 * i + 1]);
        H.u[i] = (u0 >> 16) | (u1 & 0xFFFF0000u);
        const float r0 = f[2 * i]     - __uint_as_float(u0 & 0xFFFF0000u);
        const float r1 = f[2 * i + 1] - __uint_as_float(u1 & 0xFFFF0000u);
        L.u[i] = (__float_as_uint(r0) >> 16) | (__float_as_uint(r1) & 0xFFFF0000u);
    }
    hi = H.v; lo = L.v;
}

#define MFMA3(C, Ahi, Alo, Bhi, Blo)                                          \
    C = __builtin_amdgcn_mfma_f32_16x16x32_bf16((Ahi), (Bhi), C, 0, 0, 0);    \
    C = __builtin_amdgcn_mfma_f32_16x16x32_bf16((Ahi), (Blo), C, 0, 0, 0);    \
    C = __builtin_amdgcn_mfma_f32_16x16x32_bf16((Alo), (Bhi), C, 0, 0, 0);

// XOR-swizzled 16B slot for the h-fragment buffer (bank spread, bijective)
__device__ __forceinline__ int hslot(int kf, int ln) {  // ln = n + 16*kg
    const int s = kf * 64 + ln;
    return s ^ ((s >> 4) & 3) ^ (((s >> 6) & 3) << 2);
}

__global__ __launch_bounds__(kThreads, 3) void gru_all(
    const float* __restrict__ xin,      // (B,T,F)
    const float* __restrict__ init_h,   // (L,B,U)
    const float* __restrict__ kernel0,  // (F,3U)
    const float* __restrict__ kernels,  // (L-1,U,3U)
    const float* __restrict__ rec_k,    // (L,U,3U)
    const float* __restrict__ biases,   // (L,2,3U)
    float* __restrict__ out)            // (B,T,U) seq out | (L,B,U) states
{
    __shared__ __align__(16) float smem[kSmemFloats];
    float* xstage = smem + kOffXstage;
    float* xg     = smem + kOffXg;
    float* p1     = smem + kOffP1;
    float* p2     = smem + kOffP2;
    unsigned short* hfrag = (unsigned short*)(smem + kOffHfrag);
    float* cinit  = smem + kOffCinit;
    float* biash  = smem + kOffBiash;

    const int tid  = threadIdx.x;
    const int b0   = blockIdx.x * kRows;
    const int lane = tid & 63;
    const int wv   = tid >> 6;
    const int ln15 = lane & 15;
    const int lh   = lane >> 4;
    // wave owns W-col tiles {2wv, 2wv+1} (h-dot M-dim AND x-GEMM N-dim)
    const int ntA = 2 * wv, ntB = 2 * wv + 1;
    // gate identity (valid tid<256)
    const int gr = (tid >> 7) & 1;
    const int gu = tid & 127;

    float* __restrict__ buf    = out;                        // in-place activations
    float* __restrict__ states = out + (size_t)kB * kT * kU; // final h per layer

    // zero xstage once: layer 0 writes only k 0..7; rest must be 0.
    for (int j = tid; j < kRows * kSt * kXRow; j += kThreads) xstage[j] = 0.f;

#pragma unroll 1
    for (int l = 0; l < kL; ++l) {
        // ---- W_h -> resident bf16 hi/lo fragments (once per layer) ----
        // A-frag[mt][kf]: A[m][k], m = mt*16+ln15 (W col), k = kf*32+lh*8+e
        short8 WHa[4], WLa[4], WHb[4], WLb[4];
        {
            const float* Wh = rec_k + (size_t)l * kU * kG;
#pragma unroll
            for (int kf = 0; kf < 4; ++kf) {
                float fa[8], fb[8];
#pragma unroll
                for (int e = 0; e < 8; ++e) {
                    const int k = kf * 32 + lh * 8 + e;
                    fa[e] = Wh[(size_t)k * kG + ntA * 16 + ln15];
                    fb[e] = Wh[(size_t)k * kG + ntB * 16 + ln15];
                }
                pack8(fa, WHa[kf], WLa[kf]);
                pack8(fb, WHb[kf], WLb[kf]);
            }
        }
        // biases: cinit = biasx + (col<256 ? biash : 0) folded into x-GEMM C-init
        if (tid < kG) {
            const float bx = biases[(size_t)l * 2 * kG + tid];
            const float bh = biases[(size_t)l * 2 * kG + kG + tid];
            cinit[tid] = bx + (tid < 2 * kU ? bh : 0.f);
            biash[tid] = bh;
        }
        // gate threads: h in a register; seed the h-frag buffer
        float hreg = 0.f;
        if (tid < kRows * kU) {
            hreg = init_h[(size_t)l * kB * kU + (size_t)(b0 + gr) * kU + gu];
            const int kf = gu >> 5, kg = (gu & 31) >> 3, e = gu & 7;
            const unsigned hu = __float_as_uint(hreg);
            const float lof = hreg - __uint_as_float(hu & 0xFFFF0000u);
            hfrag[hslot(kf, 2 * gr + 16 * kg) * 8 + e]     = (unsigned short)(hu >> 16);
            hfrag[hslot(kf, 2 * gr + 1 + 16 * kg) * 8 + e] = (unsigned short)(__float_as_uint(lof) >> 16);
        }
        __syncthreads();

        const int nkt = (l == 0) ? 1 : 4;  // 32-k tiles (l0: K=8, zero-padded)

#pragma unroll 1
        for (int t0 = 0; t0 < kT; t0 += kSt) {
            // ---- X1: stage x for the next 16 steps (verbatim R13) ----
            if (l == 0) {
                if (tid < 64) {
                    const int r = tid >> 5, q = tid & 31, tt = q >> 1, hf = q & 1;
                    *(float4*)&xstage[(r * kSt + tt) * kXRow + 4 * hf] =
                        *(const float4*)(xin + ((size_t)(b0 + r) * kT + (t0 + tt)) * kF + 4 * hf);
                }
            } else {
#pragma unroll
                for (int i = tid; i < 1024; i += kThreads) {
                    const int r = i >> 9, idx = i & 511, tt = idx >> 5, c4 = idx & 31;
                    *(float4*)&xstage[(r * kSt + tt) * kXRow + 4 * c4] =
                        *(const float4*)(buf + ((size_t)(b0 + r) * kT + (t0 + tt)) * kU + 4 * c4);
                }
            }
            __syncthreads();

            // ---- X2: x-GEMM via MFMA (verbatim R13) ----
            {
                const float ciA = cinit[ntA * 16 + ln15];
                const float ciB = cinit[ntB * 16 + ln15];
                f32x4 C00 = {ciA, ciA, ciA, ciA};  // [mt=0][ntA]
                f32x4 C10 = {ciA, ciA, ciA, ciA};  // [mt=1][ntA]
                f32x4 C01 = {ciB, ciB, ciB, ciB};  // [mt=0][ntB]
                f32x4 C11 = {ciB, ciB, ciB, ciB};  // [mt=1][ntB]

                const float* Wxp = (l == 0) ? kernel0
                                            : kernels + (size_t)(l - 1) * kU * kG;
                asm volatile("" : "+v"(Wxp));  // no LICM hoist across t0 loop

#pragma unroll 1
                for (int kt = 0; kt < nkt; ++kt) {
                    float fA[8], fB[8];
#pragma unroll
                    for (int eo = 0; eo < 8; ++eo) {
                        const int row = kt * 32 + lh * 8 + eo;
                        float vA = 0.f, vB = 0.f;
                        if (l != 0 || row < kF) {
                            const float* rp = Wxp + (size_t)row * kG;
                            vA = rp[ntA * 16 + ln15];
                            vB = rp[ntB * 16 + ln15];
                        }
                        fA[eo] = vA; fB[eo] = vB;
                    }
                    short8 BhiA, BloA, BhiB, BloB;
                    pack8(fA, BhiA, BloA);
                    pack8(fB, BhiB, BloB);

                    const float4* xs4 = (const float4*)xstage;
                    const int fi0 = (0 * 16 + ln15) * (kXRow / 4) + kt * 8 + lh * 2;
                    const int fi1 = (1 * 16 + ln15) * (kXRow / 4) + kt * 8 + lh * 2;
                    short8 Ahi0, Alo0, Ahi1, Alo1;
                    split8(xs4[fi0], xs4[fi0 + 1], Ahi0, Alo0);
                    split8(xs4[fi1], xs4[fi1 + 1], Ahi1, Alo1);

                    MFMA3(C00, Ahi0, Alo0, BhiA, BloA)
                    MFMA3(C10, Ahi1, Alo1, BhiA, BloA)
                    MFMA3(C01, Ahi0, Alo0, BhiB, BloB)
                    MFMA3(C11, Ahi1, Alo1, BhiB, BloB)
                }

#pragma unroll
                for (int reg = 0; reg < 4; ++reg) {
                    const int ml = lh * 4 + reg;
                    xg[(0 * kSt + ml) * kG + ntA * 16 + ln15] = C00[reg];
                    xg[(1 * kSt + ml) * kG + ntA * 16 + ln15] = C10[reg];
                    xg[(0 * kSt + ml) * kG + ntB * 16 + ln15] = C01[reg];
                    xg[(1 * kSt + ml) * kG + ntB * 16 + ln15] = C11[reg];
                }
            }
            __syncthreads();

            // ---- 16 recurrence steps: MFMA h-dot + gate ----
#pragma unroll 1
            for (int tt = 0; tt < kSt; ++tt) {
                // MFMA phase: D[m=W-col][n=(row,part)]
                {
                    f32x4 D1a = {0.f, 0.f, 0.f, 0.f};  // A=Whi, mt=ntA
                    f32x4 D1b = {0.f, 0.f, 0.f, 0.f};  // A=Whi, mt=ntB
                    f32x4 D2a = {0.f, 0.f, 0.f, 0.f};  // A=Wlo, mt=ntA
                    f32x4 D2b = {0.f, 0.f, 0.f, 0.f};  // A=Wlo, mt=ntB
#pragma unroll
                    for (int kf = 0; kf < 4; ++kf) {
                        short8 Bf = {0, 0, 0, 0, 0, 0, 0, 0};
                        if (ln15 < 4)
                            Bf = *(const short8*)&hfrag[hslot(kf, lane) * 8];
                        D1a = __builtin_amdgcn_mfma_f32_16x16x32_bf16(WHa[kf], Bf, D1a, 0, 0, 0);
                        D1b = __builtin_amdgcn_mfma_f32_16x16x32_bf16(WHb[kf], Bf, D1b, 0, 0, 0);
                        D2a = __builtin_amdgcn_mfma_f32_16x16x32_bf16(WLa[kf], Bf, D2a, 0, 0, 0);
                        D2b = __builtin_amdgcn_mfma_f32_16x16x32_bf16(WLb[kf], Bf, D2b, 0, 0, 0);
                    }
                    // D row (lh*4+reg) = W-col within tile; D col (ln15) = n
                    if (ln15 < 4) {
                        *(f32x4*)&p1[ln15 * 388 + ntA * 16 + lh * 4] = D1a;
                        *(f32x4*)&p1[ln15 * 388 + ntB * 16 + lh * 4] = D1b;
                        if ((ln15 & 1) == 0) {
                            *(f32x4*)&p2[(ln15 >> 1) * 388 + ntA * 16 + lh * 4] = D2a;
                            *(f32x4*)&p2[(ln15 >> 1) * 388 + ntB * 16 + lh * 4] = D2b;
                        }
                    }
                }
                __syncthreads();

                // gate phase (tid<256): sum bf16x3 partials, apply gates
                if (tid < kRows * kU) {
                    const float* xgp = &xg[(size_t)(gr * kSt + tt) * kG];
                    const int n0 = 2 * gr, n1 = 2 * gr + 1;
                    const float sz = p1[n0 * 388 + gu]            + p1[n1 * 388 + gu]            + p2[gr * 388 + gu];
                    const float sr = p1[n0 * 388 + kU + gu]       + p1[n1 * 388 + kU + gu]       + p2[gr * 388 + kU + gu];
                    const float sp = p1[n0 * 388 + 2 * kU + gu]   + p1[n1 * 388 + 2 * kU + gu]   + p2[gr * 388 + 2 * kU + gu];
                    const float z  = frcp(1.f + __expf(-(xgp[gu] + sz)));
                    const float rg = frcp(1.f + __expf(-(xgp[kU + gu] + sr)));
                    const float ta = xgp[2 * kU + gu] + rg * (sp + biash[2 * kU + gu]);
                    const float hh = 1.f - 2.f * frcp(1.f + __expf(2.f * ta));  // tanh
                    const float h  = z * hreg + (1.f - z) * hh;
                    hreg = h;
                    // rebuild h-frags for the next step's MFMA
                    const int kf = gu >> 5, kg = (gu & 31) >> 3, e = gu & 7;
                    const unsigned hu = __float_as_uint(h);
                    const float lof = h - __uint_as_float(hu & 0xFFFF0000u);
                    hfrag[hslot(kf, 2 * gr + 16 * kg) * 8 + e]     = (unsigned short)(hu >> 16);
                    hfrag[hslot(kf, 2 * gr + 1 + 16 * kg) * 8 + e] = (unsigned short)(__float_as_uint(lof) >> 16);
                    buf[((size_t)(b0 + gr) * kT + (t0 + tt)) * kU + gu] = h;
                }
                __syncthreads();
            }
        }

        // ---- final state of this layer ----
        if (tid < kRows * kU)
            states[(size_t)l * kB * kU + (size_t)(b0 + gr) * kU + gu] = hreg;
        __syncthreads();
    }
}

}  // namespace

extern "C" void kernel_launch(void* const* d_in, const int* in_sizes, int n_in,
                              void* d_out, int out_size, void* d_ws, size_t ws_size,
                              hipStream_t stream) {
    const float* xin     = (const float*)d_in[0];
    const float* init_h  = (const float*)d_in[1];
    const float* kernel0 = (const float*)d_in[2];
    const float* kernels = (const float*)d_in[3];
    const float* rec_k   = (const float*)d_in[4];
    const float* biases  = (const float*)d_in[5];
    float* out = (float*)d_out;

    dim3 grid(kB / kRows);   // 256 blocks, 1 per CU
    dim3 block(kThreads);    // 768 threads = 12 waves, 3 per SIMD
    gru_all<<<grid, block, 0, stream>>>(xin, init_h, kernel0, kernels, rec_k, biases, out);
}

// Round 10
// 2700.015 us; speedup vs baseline: 8.3705x; 1.0748x over previous
//
#include <hip/hip_runtime.h>
#include <math.h>

// SynchronGRU R16: layer-pipelined persistent kernel, full-N MFMA tiles.
// R15 post-mortem: MFMA h-dot worked (MfmaUtil 27, VALU 77->32) but dur flat:
// 12 waves x 16 MFMA = 192 MFMA-instr/CU/step (~930 cy matrix pipe) because
// N carried only 2 rows x hi/lo = 4/16 useful cols. Packing N full needs >=8
// rows/block; that shrinks the grid below CU count. Resolution: stop running
// 8 layers sequentially in one block.
// R16: grid 256 = 8 layers x 32 chunks(16 rows). Block (l,c) = persistent
// worker for layer l rows [16c,16c+16). Producer-consumer via device-scope
// flags (d_ws); activations cascade IN-PLACE through `out` ([r,t] read by
// layer l then overwritten by it; l+1 reads after l's flag -> strict layer
// order per location, no workspace buffers). Critical path: 2048 -> ~270
// sequential step-times. N=16 rows fills the MFMA tile exactly.
// Per step/CU: h-GEMM 24m x 1n x 4k x 3(bf16x3) = 288 MFMA + x-GEMM 288.
// W_h resident (16 short8 = 64 VGPR); W_x streamed per 2-step window
// (asm-laundered vs LICM, R10 lesson); x-D lives in registers as h-GEMM
// C-init for z/r waves (cand x-part via xg LDS since r gates only h-side).
// Handoff: __hip_atomic_ AGENT loads/stores + acquire poll / release bump.
// 81 KB LDS forces 1 block/CU -> all 256 blocks co-resident (no deadlock).

namespace {

constexpr int kB = 512;
constexpr int kT = 256;
constexpr int kF = 8;
constexpr int kU = 128;
constexpr int kG = 384;   // 3*U, gate order [z, r, h]
constexpr int kL = 8;
constexpr int kRowsB = 16;              // batch rows per block
constexpr int kChunks = kB / kRowsB;    // 32
constexpr int kThreads = 768;           // 12 waves, 3 per SIMD
constexpr int kW = 2;                   // steps per window (x-GEMM batch)

// LDS layout (floats)
constexpr int kOffXstage = 0;            // [2t][16r][132] = 4224
constexpr int kOffHrow   = 4224;         // [16r][132]     = 2112
constexpr int kOffXg     = 6336;         // [2t][16r][132] = 4224 (cand x-part)
constexpr int kOffPacc   = 10560;        // [16r][388]     = 6208
constexpr int kOffCinit  = 16768;        // [384]
constexpr int kOffBiash  = 17152;        // [384]
constexpr int kSmemFloats = 20736;       // 81 KB (pad) -> 1 block/CU
static_assert(kSmemFloats * 4 <= 160 * 1024, "LDS budget");

typedef __attribute__((ext_vector_type(8))) short short8;
typedef __attribute__((ext_vector_type(4))) float f32x4;

__device__ __forceinline__ float frcp(float x) { return __builtin_amdgcn_rcpf(x); }

#define MFMA(A, B, C) __builtin_amdgcn_mfma_f32_16x16x32_bf16((A), (B), (C), 0, 0, 0)

// split 8 fp32 (two float4, consecutive k) into bf16-hi / bf16-lo fragments
__device__ __forceinline__ void split8(const float4 a, const float4 b,
                                       short8& hi, short8& lo) {
    union { unsigned u[4]; short8 v; } H, L;
    const float f[8] = {a.x, a.y, a.z, a.w, b.x, b.y, b.z, b.w};
#pragma unroll
    for (int i = 0; i < 4; ++i) {
        const unsigned u0 = __float_as_uint(f[2 * i]);
        const unsigned u1 = __float_as_uint(f[2 * i + 1]);
        H.u[i] = (u0 >> 16) | (u1 & 0xFFFF0000u);
        const float r0 = f[2 * i]     - __uint_as_float(u0 & 0xFFFF0000u);
        const float r1 = f[2 * i + 1] - __uint_as_float(u1 & 0xFFFF0000u);
        L.u[i] = (__float_as_uint(r0) >> 16) | (__float_as_uint(r1) & 0xFFFF0000u);
    }
    hi = H.v; lo = L.v;
}

__device__ __forceinline__ void pack8(const float* f, short8& hi, short8& lo) {
    union { unsigned u[4]; short8 v; } H, L;
#pragma unroll
    for (int i = 0; i < 4; ++i) {
        const unsigned u0 = __float_as_uint(f[2 * i]);
        const unsigned u1 = __float_as_uint(f[2 * i + 1]);
        H.u[i] = (u0 >> 16) | (u1 & 0xFFFF0000u);
        const float r0 = f[2 * i]     - __uint_as_float(u0 & 0xFFFF0000u);
        const float r1 = f[2 * i + 1] - __uint_as_float(u1 & 0xFFFF0000u);
        L.u[i] = (__float_as_uint(r0) >> 16) | (__float_as_uint(r1) & 0xFFFF0000u);
    }
    hi = H.v; lo = L.v;
}

__global__ __launch_bounds__(kThreads, 3) void gru_all(
    const float* __restrict__ xin,      // (B,T,F)
    const float* __restrict__ init_h,   // (L,B,U)
    const float* __restrict__ kernel0,  // (F,3U)
    const float* __restrict__ kernels,  // (L-1,U,3U)
    const float* __restrict__ rec_k,    // (L,U,3U)
    const float* __restrict__ biases,   // (L,2,3U)
    float* __restrict__ out,            // (B,T,U) seq out | (L,B,U) states
    unsigned* __restrict__ flags)       // [L][32] step counters (d_ws)
{
    __shared__ __align__(16) float smem[kSmemFloats];
    float* xstage = smem + kOffXstage;
    float* hrow   = smem + kOffHrow;
    float* xg     = smem + kOffXg;
    float* pacc   = smem + kOffPacc;
    float* cinit  = smem + kOffCinit;
    float* biash  = smem + kOffBiash;

    const int tid  = threadIdx.x;
    const int lane = tid & 63;
    const int wv   = tid >> 6;
    const int ln15 = lane & 15;
    const int lh   = lane >> 4;
    const int lay  = blockIdx.x >> 5;        // layer 0..7
    const int chk  = blockIdx.x & 31;        // row chunk 0..31
    const int r0   = chk * kRowsB;
    const int mtA  = 2 * wv, mtB = 2 * wv + 1;  // m-tiles (W-col tiles 0..23)
    const bool zr  = (wv < 8);               // tiles 0..15 = z,r gates
    const int grow = tid >> 5;               // gate row (tid<512)
    const int gu0  = (tid & 31) * 4;         // gate unit base

    float* __restrict__ buf    = out;
    float* __restrict__ states = out + (size_t)kB * kT * kU;
    const float* Wh = rec_k + (size_t)lay * kU * kG;
    const float* WxBase = (lay == 0) ? kernel0 : kernels + (size_t)(lay - 1) * kU * kG;
    const int nkf = (lay == 0) ? 1 : 4;

    // zero xstage once (layer 0 relies on k>=8 staying zero)
    for (int j = tid; j < kW * kRowsB * 132; j += kThreads) xstage[j] = 0.f;

    // ---- W_h -> resident bf16 hi/lo A-fragments (once) ----
    short8 WhiA[4], WloA[4], WhiB[4], WloB[4];
#pragma unroll
    for (int kf = 0; kf < 4; ++kf) {
        float fa[8], fb[8];
#pragma unroll
        for (int e = 0; e < 8; ++e) {
            const int k = kf * 32 + lh * 8 + e;
            fa[e] = Wh[(size_t)k * kG + mtA * 16 + ln15];
            fb[e] = Wh[(size_t)k * kG + mtB * 16 + ln15];
        }
        pack8(fa, WhiA[kf], WloA[kf]);
        pack8(fb, WhiB[kf], WloB[kf]);
    }
    if (tid < kG) {
        const float bx = biases[(size_t)lay * 2 * kG + tid];
        const float bh = biases[(size_t)lay * 2 * kG + kG + tid];
        cinit[tid] = bx + (tid < 2 * kU ? bh : 0.f);  // z,r: bx+bh; cand: bx
        biash[tid] = bh;
    }
    float hr0 = 0.f, hr1 = 0.f, hr2 = 0.f, hr3 = 0.f;
    if (tid < 512) {
        const float* hp = init_h + (size_t)lay * kB * kU + (size_t)(r0 + grow) * kU + gu0;
        hr0 = hp[0]; hr1 = hp[1]; hr2 = hp[2]; hr3 = hp[3];
        float4 hv = {hr0, hr1, hr2, hr3};
        *(float4*)&hrow[grow * 132 + gu0] = hv;
    }
    __syncthreads();

#pragma unroll 1
    for (int t0 = 0; t0 < kT; t0 += kW) {
        // ---- acquire x window ----
        if (lay > 0) {
            if (tid == 0) {
                while ((int)__hip_atomic_load(&flags[(lay - 1) * kChunks + chk],
                                              __ATOMIC_ACQUIRE,
                                              __HIP_MEMORY_SCOPE_AGENT) < t0 + kW)
                    __builtin_amdgcn_s_sleep(2);
            }
            __syncthreads();
            for (int i = tid; i < kW * kRowsB * kU; i += kThreads) {
                const int t = i >> 11, rr = (i >> 7) & 15, k = i & 127;
                const float v = __hip_atomic_load(
                    &buf[((size_t)(r0 + rr) * kT + (t0 + t)) * kU + k],
                    __ATOMIC_RELAXED, __HIP_MEMORY_SCOPE_AGENT);
                xstage[(t * kRowsB + rr) * 132 + k] = v;
            }
        } else {
            for (int i = tid; i < kW * kRowsB * kF; i += kThreads) {
                const int t = i >> 7, rr = (i >> 3) & 15, k = i & 7;
                xstage[(t * kRowsB + rr) * 132 + k] =
                    xin[((size_t)(r0 + rr) * kT + (t0 + t)) * kF + k];
            }
        }
        __syncthreads();

        // ---- x-GEMM (window of 2): A=W_x streamed, B=x, bias in C-init ----
        f32x4 xDA0, xDA1, xDB0, xDB1;
        {
            const f32x4 cA = *(const f32x4*)&cinit[mtA * 16 + lh * 4];
            const f32x4 cB = *(const f32x4*)&cinit[mtB * 16 + lh * 4];
            xDA0 = cA; xDA1 = cA; xDB0 = cB; xDB1 = cB;
            const float* Wxp = WxBase;
            asm volatile("" : "+v"(Wxp));  // no LICM hoist across windows
#pragma unroll 1
            for (int kf = 0; kf < nkf; ++kf) {
                float fa[8], fb[8];
#pragma unroll
                for (int e = 0; e < 8; ++e) {
                    const int k = kf * 32 + lh * 8 + e;
                    const bool valid = (lay != 0) || (k < kF);
                    fa[e] = valid ? Wxp[(size_t)k * kG + mtA * 16 + ln15] : 0.f;
                    fb[e] = valid ? Wxp[(size_t)k * kG + mtB * 16 + ln15] : 0.f;
                }
                short8 AhiA, AloA, AhiB, AloB;
                pack8(fa, AhiA, AloA);
                pack8(fb, AhiB, AloB);
                {
                    const float4 x0 = *(const float4*)&xstage[ln15 * 132 + kf * 32 + lh * 8];
                    const float4 x1 = *(const float4*)&xstage[ln15 * 132 + kf * 32 + lh * 8 + 4];
                    short8 Bh, Bl; split8(x0, x1, Bh, Bl);
                    xDA0 = MFMA(AhiA, Bh, xDA0); xDA0 = MFMA(AhiA, Bl, xDA0); xDA0 = MFMA(AloA, Bh, xDA0);
                    xDB0 = MFMA(AhiB, Bh, xDB0); xDB0 = MFMA(AhiB, Bl, xDB0); xDB0 = MFMA(AloB, Bh, xDB0);
                }
                {
                    const float4 x0 = *(const float4*)&xstage[(16 + ln15) * 132 + kf * 32 + lh * 8];
                    const float4 x1 = *(const float4*)&xstage[(16 + ln15) * 132 + kf * 32 + lh * 8 + 4];
                    short8 Bh, Bl; split8(x0, x1, Bh, Bl);
                    xDA1 = MFMA(AhiA, Bh, xDA1); xDA1 = MFMA(AhiA, Bl, xDA1); xDA1 = MFMA(AloA, Bh, xDA1);
                    xDB1 = MFMA(AhiB, Bh, xDB1); xDB1 = MFMA(AhiB, Bl, xDB1); xDB1 = MFMA(AloB, Bh, xDB1);
                }
            }
            if (!zr) {  // cand x-part -> LDS for the gate phase
                *(f32x4*)&xg[(0 * 16 + ln15) * 132 + (mtA - 16) * 16 + lh * 4] = xDA0;
                *(f32x4*)&xg[(1 * 16 + ln15) * 132 + (mtA - 16) * 16 + lh * 4] = xDA1;
                *(f32x4*)&xg[(0 * 16 + ln15) * 132 + (mtB - 16) * 16 + lh * 4] = xDB0;
                *(f32x4*)&xg[(1 * 16 + ln15) * 132 + (mtB - 16) * 16 + lh * 4] = xDB1;
            }
        }

        // ---- 2 recurrence steps ----
#pragma unroll
        for (int tt = 0; tt < kW; ++tt) {
            {
                f32x4 DA, DB;
                if (zr) { DA = tt ? xDA1 : xDA0; DB = tt ? xDB1 : xDB0; }
                else    { f32x4 Z = {0.f, 0.f, 0.f, 0.f}; DA = Z; DB = Z; }
#pragma unroll
                for (int kf = 0; kf < 4; ++kf) {
                    const float4 h0 = *(const float4*)&hrow[ln15 * 132 + kf * 32 + lh * 8];
                    const float4 h1 = *(const float4*)&hrow[ln15 * 132 + kf * 32 + lh * 8 + 4];
                    short8 Bh, Bl; split8(h0, h1, Bh, Bl);
                    DA = MFMA(WhiA[kf], Bh, DA); DA = MFMA(WhiA[kf], Bl, DA); DA = MFMA(WloA[kf], Bh, DA);
                    DB = MFMA(WhiB[kf], Bh, DB); DB = MFMA(WhiB[kf], Bl, DB); DB = MFMA(WloB[kf], Bh, DB);
                }
                *(f32x4*)&pacc[ln15 * 388 + mtA * 16 + lh * 4] = DA;
                *(f32x4*)&pacc[ln15 * 388 + mtB * 16 + lh * 4] = DB;
            }
            __syncthreads();

            if (tid < 512) {
                const float* pr = &pacc[grow * 388];
                const f32x4 sz4 = *(const f32x4*)&pr[gu0];
                const f32x4 sr4 = *(const f32x4*)&pr[kU + gu0];
                const f32x4 sh4 = *(const f32x4*)&pr[2 * kU + gu0];
                const f32x4 sx4 = *(const f32x4*)&xg[(tt * 16 + grow) * 132 + gu0];
                const f32x4 bh4 = *(const f32x4*)&biash[2 * kU + gu0];
                const float ho[4] = {hr0, hr1, hr2, hr3};
                float hn[4];
#pragma unroll
                for (int j = 0; j < 4; ++j) {
                    const float z  = frcp(1.f + __expf(-sz4[j]));
                    const float rg = frcp(1.f + __expf(-sr4[j]));
                    const float ta = sx4[j] + rg * (sh4[j] + bh4[j]);
                    const float hh = 1.f - 2.f * frcp(1.f + __expf(2.f * ta));
                    hn[j] = z * ho[j] + (1.f - z) * hh;
                }
                hr0 = hn[0]; hr1 = hn[1]; hr2 = hn[2]; hr3 = hn[3];
                float4 hv = {hr0, hr1, hr2, hr3};
                *(float4*)&hrow[grow * 132 + gu0] = hv;
                float* bp = &buf[((size_t)(r0 + grow) * kT + (t0 + tt)) * kU + gu0];
                __hip_atomic_store(&bp[0], hr0, __ATOMIC_RELAXED, __HIP_MEMORY_SCOPE_AGENT);
                __hip_atomic_store(&bp[1], hr1, __ATOMIC_RELAXED, __HIP_MEMORY_SCOPE_AGENT);
                __hip_atomic_store(&bp[2], hr2, __ATOMIC_RELAXED, __HIP_MEMORY_SCOPE_AGENT);
                __hip_atomic_store(&bp[3], hr3, __ATOMIC_RELAXED, __HIP_MEMORY_SCOPE_AGENT);
            }
            __syncthreads();
        }

        // publish window (stores drained by the barrier's vmcnt wait)
        if (tid == 0) {
            __threadfence();
            __hip_atomic_fetch_add(&flags[lay * kChunks + chk], (unsigned)kW,
                                   __ATOMIC_RELEASE, __HIP_MEMORY_SCOPE_AGENT);
        }
    }

    // ---- final state of this layer ----
    if (tid < 512) {
        float* sp = &states[(size_t)lay * kB * kU + (size_t)(r0 + grow) * kU + gu0];
        sp[0] = hr0; sp[1] = hr1; sp[2] = hr2; sp[3] = hr3;
    }
}

}  // namespace

extern "C" void kernel_launch(void* const* d_in, const int* in_sizes, int n_in,
                              void* d_out, int out_size, void* d_ws, size_t ws_size,
                              hipStream_t stream) {
    const float* xin     = (const float*)d_in[0];
    const float* init_h  = (const float*)d_in[1];
    const float* kernel0 = (const float*)d_in[2];
    const float* kernels = (const float*)d_in[3];
    const float* rec_k   = (const float*)d_in[4];
    const float* biases  = (const float*)d_in[5];
    float* out = (float*)d_out;
    unsigned* flags = (unsigned*)d_ws;

    hipMemsetAsync(d_ws, 0, kL * kChunks * sizeof(unsigned), stream);
    dim3 grid(kL * kChunks);   // 256 blocks = 8 layers x 32 chunks, 1 per CU
    dim3 block(kThreads);      // 768 threads = 12 waves, 3 per SIMD
    gru_all<<<grid, block, 0, stream>>>(xin, init_h, kernel0, kernels, rec_k,
                                        biases, out, flags);
}

// Round 11
// 1218.896 us; speedup vs baseline: 18.5419x; 2.2151x over previous
//
#include <hip/hip_runtime.h>
#include <math.h>

// SynchronGRU R17: layer pipeline with CHEAP handoff (relaxed atomics only)
// and kW=4 window amortization.
// R16 post-mortem: pipeline correct but 21 us/window vs ~2 us compute. The
// residue was handoff machinery: __threadfence + RELEASE/ACQUIRE lower to
// L2 writeback/invalidate on multi-XCD CDNA (WRITE_SIZE 0.53 -> 2.1 GB =
// flush storm), paid 128x per layer at kW=2.
// R17: (1) kW=4: half the handoffs, x-GEMM batches 4 steps, W_x streamed
// half as often. (2) NO fences: all cross-XCD data moves via agent-scope
// ATOMIC loads/stores (execute at IC, never dirty in local L2), so there is
// nothing to flush; __syncthreads before publish already drains each wave's
// stores (compiler emits s_waitcnt vmcnt(0) before s_barrier), so a RELAXED
// flag bump suffices; consumer polls RELAXED (no invalidates). (3) 8-byte
// atomic ulong x-reads / h-stores halve the handoff op count.
// Everything else from R16: grid 256 = 8 layers x 32 chunks(16 rows),
// in-place activation cascade through `out`, W_h resident as bf16 hi/lo
// A-frags, bf16x3 MFMA for both GEMMs, biases folded into C-init.

namespace {

constexpr int kB = 512;
constexpr int kT = 256;
constexpr int kF = 8;
constexpr int kU = 128;
constexpr int kG = 384;   // 3*U, gate order [z, r, h]
constexpr int kL = 8;
constexpr int kRowsB = 16;              // batch rows per block
constexpr int kChunks = kB / kRowsB;    // 32
constexpr int kThreads = 768;           // 12 waves, 3 per SIMD
constexpr int kW = 4;                   // steps per window

// LDS layout (floats)
constexpr int kOffXstage = 0;            // [4t][16r][132] = 8448
constexpr int kOffHrow   = 8448;         // [16r][132]     = 2112
constexpr int kOffXg     = 10560;        // [4t][16r][132] = 8448 (cand x-part)
constexpr int kOffPacc   = 19008;        // [16r][388]     = 6208
constexpr int kOffCinit  = 25216;        // [384]
constexpr int kOffBiash  = 25600;        // [384]
constexpr int kSmemFloats = 25984;       // 101.5 KB -> 1 block/CU
static_assert(kSmemFloats * 4 <= 160 * 1024, "LDS budget");

typedef __attribute__((ext_vector_type(8))) short short8;
typedef __attribute__((ext_vector_type(4))) float f32x4;

__device__ __forceinline__ float frcp(float x) { return __builtin_amdgcn_rcpf(x); }

#define MFMA(A, B, C) __builtin_amdgcn_mfma_f32_16x16x32_bf16((A), (B), (C), 0, 0, 0)

__device__ __forceinline__ void split8(const float4 a, const float4 b,
                                       short8& hi, short8& lo) {
    union { unsigned u[4]; short8 v; } H, L;
    const float f[8] = {a.x, a.y, a.z, a.w, b.x, b.y, b.z, b.w};
#pragma unroll
    for (int i = 0; i < 4; ++i) {
        const unsigned u0 = __float_as_uint(f[2 * i]);
        const unsigned u1 = __float_as_uint(f[2 * i + 1]);
        H.u[i] = (u0 >> 16) | (u1 & 0xFFFF0000u);
        const float r0 = f[2 * i]     - __uint_as_float(u0 & 0xFFFF0000u);
        const float r1 = f[2 * i + 1] - __uint_as_float(u1 & 0xFFFF0000u);
        L.u[i] = (__float_as_uint(r0) >> 16) | (__float_as_uint(r1) & 0xFFFF0000u);
    }
    hi = H.v; lo = L.v;
}

__device__ __forceinline__ void pack8(const float* f, short8& hi, short8& lo) {
    union { unsigned u[4]; short8 v; } H, L;
#pragma unroll
    for (int i = 0; i < 4; ++i) {
        const unsigned u0 = __float_as_uint(f[2 * i]);
        const unsigned u1 = __float_as_uint(f[2 * i + 1]);
        H.u[i] = (u0 >> 16) | (u1 & 0xFFFF0000u);
        const float r0 = f[2 * i]     - __uint_as_float(u0 & 0xFFFF0000u);
        const float r1 = f[2 * i + 1] - __uint_as_float(u1 & 0xFFFF0000u);
        L.u[i] = (__float_as_uint(r0) >> 16) | (__float_as_uint(r1) & 0xFFFF0000u);
    }
    hi = H.v; lo = L.v;
}

__global__ __launch_bounds__(kThreads, 3) void gru_all(
    const float* __restrict__ xin,      // (B,T,F)
    const float* __restrict__ init_h,   // (L,B,U)
    const float* __restrict__ kernel0,  // (F,3U)
    const float* __restrict__ kernels,  // (L-1,U,3U)
    const float* __restrict__ rec_k,    // (L,U,3U)
    const float* __restrict__ biases,   // (L,2,3U)
    float* __restrict__ out,            // (B,T,U) seq out | (L,B,U) states
    unsigned* __restrict__ flags)       // [L][32] step counters (d_ws)
{
    __shared__ __align__(16) float smem[kSmemFloats];
    float* xstage = smem + kOffXstage;
    float* hrow   = smem + kOffHrow;
    float* xg     = smem + kOffXg;
    float* pacc   = smem + kOffPacc;
    float* cinit  = smem + kOffCinit;
    float* biash  = smem + kOffBiash;

    const int tid  = threadIdx.x;
    const int lane = tid & 63;
    const int wv   = tid >> 6;
    const int ln15 = lane & 15;
    const int lh   = lane >> 4;
    const int lay  = blockIdx.x >> 5;        // layer 0..7
    const int chk  = blockIdx.x & 31;        // row chunk 0..31
    const int r0   = chk * kRowsB;
    const int mtA  = 2 * wv, mtB = 2 * wv + 1;  // W-col tiles 0..23
    const bool zr  = (wv < 8);               // tiles 0..15 = z,r gates
    const int grow = tid >> 5;               // gate row (tid<512)
    const int gu0  = (tid & 31) * 4;         // gate unit base

    float* __restrict__ buf    = out;
    float* __restrict__ states = out + (size_t)kB * kT * kU;
    const float* Wh = rec_k + (size_t)lay * kU * kG;
    const float* WxBase = (lay == 0) ? kernel0 : kernels + (size_t)(lay - 1) * kU * kG;
    const int nkf = (lay == 0) ? 1 : 4;

    // zero xstage once (layer 0 relies on k>=8 staying zero)
    for (int j = tid; j < kW * kRowsB * 132; j += kThreads) xstage[j] = 0.f;

    // ---- W_h -> resident bf16 hi/lo A-fragments (once) ----
    short8 WhiA[4], WloA[4], WhiB[4], WloB[4];
#pragma unroll
    for (int kf = 0; kf < 4; ++kf) {
        float fa[8], fb[8];
#pragma unroll
        for (int e = 0; e < 8; ++e) {
            const int k = kf * 32 + lh * 8 + e;
            fa[e] = Wh[(size_t)k * kG + mtA * 16 + ln15];
            fb[e] = Wh[(size_t)k * kG + mtB * 16 + ln15];
        }
        pack8(fa, WhiA[kf], WloA[kf]);
        pack8(fb, WhiB[kf], WloB[kf]);
    }
    if (tid < kG) {
        const float bx = biases[(size_t)lay * 2 * kG + tid];
        const float bh = biases[(size_t)lay * 2 * kG + kG + tid];
        cinit[tid] = bx + (tid < 2 * kU ? bh : 0.f);  // z,r: bx+bh; cand: bx
        biash[tid] = bh;
    }
    float hr0 = 0.f, hr1 = 0.f, hr2 = 0.f, hr3 = 0.f;
    if (tid < 512) {
        const float* hp = init_h + (size_t)lay * kB * kU + (size_t)(r0 + grow) * kU + gu0;
        hr0 = hp[0]; hr1 = hp[1]; hr2 = hp[2]; hr3 = hp[3];
        float4 hv = {hr0, hr1, hr2, hr3};
        *(float4*)&hrow[grow * 132 + gu0] = hv;
    }
    __syncthreads();

#pragma unroll 1
    for (int t0 = 0; t0 < kT; t0 += kW) {
        // ---- acquire x window (RELAXED poll; atomic data path needs no inv) ----
        if (lay > 0) {
            if (tid == 0) {
                while ((int)__hip_atomic_load(&flags[(lay - 1) * kChunks + chk],
                                              __ATOMIC_RELAXED,
                                              __HIP_MEMORY_SCOPE_AGENT) < t0 + kW)
                    __builtin_amdgcn_s_sleep(2);
            }
            __syncthreads();
            // 8-byte atomic reads from IC (bypass possibly-stale local caches)
            const unsigned long long* bp =
                (const unsigned long long*)buf;
            for (int i = tid; i < kW * kRowsB * (kU / 2); i += kThreads) {
                const int t = i >> 10, rr = (i >> 6) & 15, kp = i & 63;
                const unsigned long long v = __hip_atomic_load(
                    &bp[(((size_t)(r0 + rr) * kT + (t0 + t)) * kU) / 2 + kp],
                    __ATOMIC_RELAXED, __HIP_MEMORY_SCOPE_AGENT);
                xstage[(t * kRowsB + rr) * 132 + 2 * kp]     = __uint_as_float((unsigned)v);
                xstage[(t * kRowsB + rr) * 132 + 2 * kp + 1] = __uint_as_float((unsigned)(v >> 32));
            }
        } else {
            for (int i = tid; i < kW * kRowsB * kF; i += kThreads) {
                const int t = i >> 7, rr = (i >> 3) & 15, k = i & 7;
                xstage[(t * kRowsB + rr) * 132 + k] =
                    xin[((size_t)(r0 + rr) * kT + (t0 + t)) * kF + k];
            }
        }
        __syncthreads();

        // ---- x-GEMM (window of 4): A=W_x streamed, B=x, bias in C-init ----
        f32x4 xDA[kW], xDB[kW];
        {
            const f32x4 cA = *(const f32x4*)&cinit[mtA * 16 + lh * 4];
            const f32x4 cB = *(const f32x4*)&cinit[mtB * 16 + lh * 4];
#pragma unroll
            for (int tt = 0; tt < kW; ++tt) { xDA[tt] = cA; xDB[tt] = cB; }
            const float* Wxp = WxBase;
            asm volatile("" : "+v"(Wxp));  // no LICM hoist across windows
#pragma unroll 1
            for (int kf = 0; kf < nkf; ++kf) {
                float fa[8], fb[8];
#pragma unroll
                for (int e = 0; e < 8; ++e) {
                    const int k = kf * 32 + lh * 8 + e;
                    const bool valid = (lay != 0) || (k < kF);
                    fa[e] = valid ? Wxp[(size_t)k * kG + mtA * 16 + ln15] : 0.f;
                    fb[e] = valid ? Wxp[(size_t)k * kG + mtB * 16 + ln15] : 0.f;
                }
                short8 AhiA, AloA, AhiB, AloB;
                pack8(fa, AhiA, AloA);
                pack8(fb, AhiB, AloB);
#pragma unroll
                for (int tt = 0; tt < kW; ++tt) {
                    const float4 x0 = *(const float4*)&xstage[(tt * 16 + ln15) * 132 + kf * 32 + lh * 8];
                    const float4 x1 = *(const float4*)&xstage[(tt * 16 + ln15) * 132 + kf * 32 + lh * 8 + 4];
                    short8 Bh, Bl; split8(x0, x1, Bh, Bl);
                    xDA[tt] = MFMA(AhiA, Bh, xDA[tt]); xDA[tt] = MFMA(AhiA, Bl, xDA[tt]); xDA[tt] = MFMA(AloA, Bh, xDA[tt]);
                    xDB[tt] = MFMA(AhiB, Bh, xDB[tt]); xDB[tt] = MFMA(AhiB, Bl, xDB[tt]); xDB[tt] = MFMA(AloB, Bh, xDB[tt]);
                }
            }
            if (!zr) {  // cand x-part -> LDS for the gate phase
#pragma unroll
                for (int tt = 0; tt < kW; ++tt) {
                    *(f32x4*)&xg[(tt * 16 + ln15) * 132 + (mtA - 16) * 16 + lh * 4] = xDA[tt];
                    *(f32x4*)&xg[(tt * 16 + ln15) * 132 + (mtB - 16) * 16 + lh * 4] = xDB[tt];
                }
            }
        }

        // ---- kW recurrence steps ----
#pragma unroll
        for (int tt = 0; tt < kW; ++tt) {
            {
                f32x4 DA, DB;
                if (zr) { DA = xDA[tt]; DB = xDB[tt]; }
                else    { f32x4 Z = {0.f, 0.f, 0.f, 0.f}; DA = Z; DB = Z; }
#pragma unroll
                for (int kf = 0; kf < 4; ++kf) {
                    const float4 h0 = *(const float4*)&hrow[ln15 * 132 + kf * 32 + lh * 8];
                    const float4 h1 = *(const float4*)&hrow[ln15 * 132 + kf * 32 + lh * 8 + 4];
                    short8 Bh, Bl; split8(h0, h1, Bh, Bl);
                    DA = MFMA(WhiA[kf], Bh, DA); DA = MFMA(WhiA[kf], Bl, DA); DA = MFMA(WloA[kf], Bh, DA);
                    DB = MFMA(WhiB[kf], Bh, DB); DB = MFMA(WhiB[kf], Bl, DB); DB = MFMA(WloB[kf], Bh, DB);
                }
                *(f32x4*)&pacc[ln15 * 388 + mtA * 16 + lh * 4] = DA;
                *(f32x4*)&pacc[ln15 * 388 + mtB * 16 + lh * 4] = DB;
            }
            __syncthreads();

            if (tid < 512) {
                const float* pr = &pacc[grow * 388];
                const f32x4 sz4 = *(const f32x4*)&pr[gu0];
                const f32x4 sr4 = *(const f32x4*)&pr[kU + gu0];
                const f32x4 sh4 = *(const f32x4*)&pr[2 * kU + gu0];
                const f32x4 sx4 = *(const f32x4*)&xg[(tt * 16 + grow) * 132 + gu0];
                const f32x4 bh4 = *(const f32x4*)&biash[2 * kU + gu0];
                const float ho[4] = {hr0, hr1, hr2, hr3};
                float hn[4];
#pragma unroll
                for (int j = 0; j < 4; ++j) {
                    const float z  = frcp(1.f + __expf(-sz4[j]));
                    const float rg = frcp(1.f + __expf(-sr4[j]));
                    const float ta = sx4[j] + rg * (sh4[j] + bh4[j]);
                    const float hh = 1.f - 2.f * frcp(1.f + __expf(2.f * ta));
                    hn[j] = z * ho[j] + (1.f - z) * hh;
                }
                hr0 = hn[0]; hr1 = hn[1]; hr2 = hn[2]; hr3 = hn[3];
                float4 hv = {hr0, hr1, hr2, hr3};
                *(float4*)&hrow[grow * 132 + gu0] = hv;
                // 8-byte atomic write-through to IC (visible to consumer XCDs)
                unsigned long long u01 =
                    (unsigned long long)__float_as_uint(hr0) |
                    ((unsigned long long)__float_as_uint(hr1) << 32);
                unsigned long long u23 =
                    (unsigned long long)__float_as_uint(hr2) |
                    ((unsigned long long)__float_as_uint(hr3) << 32);
                unsigned long long* bp = (unsigned long long*)
                    &buf[((size_t)(r0 + grow) * kT + (t0 + tt)) * kU + gu0];
                __hip_atomic_store(&bp[0], u01, __ATOMIC_RELAXED, __HIP_MEMORY_SCOPE_AGENT);
                __hip_atomic_store(&bp[1], u23, __ATOMIC_RELAXED, __HIP_MEMORY_SCOPE_AGENT);
            }
            __syncthreads();
        }

        // publish window: the step-loop's final __syncthreads already drained
        // every wave's stores (compiler emits s_waitcnt vmcnt(0) before
        // s_barrier), so a RELAXED bump is sufficient -- no fence, no flush.
        if (tid == 0) {
            __hip_atomic_fetch_add(&flags[lay * kChunks + chk], (unsigned)kW,
                                   __ATOMIC_RELAXED, __HIP_MEMORY_SCOPE_AGENT);
        }
    }

    // ---- final state of this layer ----
    if (tid < 512) {
        float* sp = &states[(size_t)lay * kB * kU + (size_t)(r0 + grow) * kU + gu0];
        sp[0] = hr0; sp[1] = hr1; sp[2] = hr2; sp[3] = hr3;
    }
}

}  // namespace

extern "C" void kernel_launch(void* const* d_in, const int* in_sizes, int n_in,
                              void* d_out, int out_size, void* d_ws, size_t ws_size,
                              hipStream_t stream) {
    const float* xin     = (const float*)d_in[0];
    const float* init_h  = (const float*)d_in[1];
    const float* kernel0 = (const float*)d_in[2];
    const float* kernels = (const float*)d_in[3];
    const float* rec_k   = (const float*)d_in[4];
    const float* biases  = (const float*)d_in[5];
    float* out = (float*)d_out;
    unsigned* flags = (unsigned*)d_ws;

    hipMemsetAsync(d_ws, 0, kL * kChunks * sizeof(unsigned), stream);
    dim3 grid(kL * kChunks);   // 256 blocks = 8 layers x 32 chunks, 1 per CU
    dim3 block(kThreads);      // 768 threads = 12 waves, 3 per SIMD
    gru_all<<<grid, block, 0, stream>>>(xin, init_h, kernel0, kernels, rec_k,
                                        biases, out, flags);
}

// Round 12
// 907.650 us; speedup vs baseline: 24.9001x; 1.3429x over previous
//
#include <hip/hip_runtime.h>
#include <math.h>

// SynchronGRU R18: hoist bf16 hi/lo packing to the data producers.
// R17 post-mortem (1275 us): pipeline healthy, but VALUBusy 53% = 10.5 us
// VALU/window vs 4 us MFMA. ~60% of that VALU is split8() of h and x inside
// the MFMA loops -- and B-fragments are IDENTICAL across all 12 waves (only
// A differs), so the split work is duplicated 12x.
// R18: h is packed ONCE per step by the gate phase (which computes it anyway)
// into hpk_hi/lo[16][136] u16; x is packed during the IC staging pass into
// xpk_hi/lo[kW*16][136]. MFMA loops read short8 B-frags via ds_read_b128
// (row stride 272 B -> 2-way bank access, free). f32 xstage/hrow deleted.
// Numerics bit-identical (same truncation split, same MFMA order).
// Shell from R17: grid 256 = 8 layers x 32 chunks(16 rows); in-place
// activation cascade through `out` with relaxed agent-scope atomics; kW=4;
// W_h resident bf16 hi/lo A-frags; biases folded into C-init; 1 block/CU
// (103 KB LDS) so all 256 blocks co-resident.

namespace {

constexpr int kB = 512;
constexpr int kT = 256;
constexpr int kF = 8;
constexpr int kU = 128;
constexpr int kG = 384;   // 3*U, gate order [z, r, h]
constexpr int kL = 8;
constexpr int kRowsB = 16;              // batch rows per block
constexpr int kChunks = kB / kRowsB;    // 32
constexpr int kThreads = 768;           // 12 waves, 3 per SIMD
constexpr int kW = 4;                   // steps per window
constexpr int kPk = 136;                // packed row stride (u16), 272 B

// LDS layout (floats)
constexpr int kOffXpkHi = 0;                         // u16[64][136] = 4352 f
constexpr int kOffXpkLo = 4352;                      // u16[64][136] = 4352 f
constexpr int kOffHpkHi = 8704;                      // u16[16][136] = 1088 f
constexpr int kOffHpkLo = 9792;                      // u16[16][136] = 1088 f
constexpr int kOffXg    = 10880;                     // f32 [4t][16r][132] = 8448
constexpr int kOffPacc  = 19328;                     // f32 [16r][388] = 6208
constexpr int kOffCinit = 25536;                     // [384]
constexpr int kOffBiash = 25920;                     // [384]
constexpr int kSmemFloats = 26304;                   // 102.75 KB -> 1 block/CU
static_assert(kSmemFloats * 4 <= 160 * 1024, "LDS budget");

typedef __attribute__((ext_vector_type(8))) short short8;
typedef __attribute__((ext_vector_type(4))) float f32x4;

__device__ __forceinline__ float frcp(float x) { return __builtin_amdgcn_rcpf(x); }

#define MFMA(A, B, C) __builtin_amdgcn_mfma_f32_16x16x32_bf16((A), (B), (C), 0, 0, 0)

__device__ __forceinline__ void pack8(const float* f, short8& hi, short8& lo) {
    union { unsigned u[4]; short8 v; } H, L;
#pragma unroll
    for (int i = 0; i < 4; ++i) {
        const unsigned u0 = __float_as_uint(f[2 * i]);
        const unsigned u1 = __float_as_uint(f[2 * i + 1]);
        H.u[i] = (u0 >> 16) | (u1 & 0xFFFF0000u);
        const float r0 = f[2 * i]     - __uint_as_float(u0 & 0xFFFF0000u);
        const float r1 = f[2 * i + 1] - __uint_as_float(u1 & 0xFFFF0000u);
        L.u[i] = (__float_as_uint(r0) >> 16) | (__float_as_uint(r1) & 0xFFFF0000u);
    }
    hi = H.v; lo = L.v;
}

// pack one float into (hi, lo) bf16 truncation pair
__device__ __forceinline__ void pack1(const float f, unsigned short& hi,
                                      unsigned short& lo) {
    const unsigned u = __float_as_uint(f);
    hi = (unsigned short)(u >> 16);
    const float r = f - __uint_as_float(u & 0xFFFF0000u);
    lo = (unsigned short)(__float_as_uint(r) >> 16);
}

__global__ __launch_bounds__(kThreads, 3) void gru_all(
    const float* __restrict__ xin,      // (B,T,F)
    const float* __restrict__ init_h,   // (L,B,U)
    const float* __restrict__ kernel0,  // (F,3U)
    const float* __restrict__ kernels,  // (L-1,U,3U)
    const float* __restrict__ rec_k,    // (L,U,3U)
    const float* __restrict__ biases,   // (L,2,3U)
    float* __restrict__ out,            // (B,T,U) seq out | (L,B,U) states
    unsigned* __restrict__ flags)       // [L][32] step counters (d_ws)
{
    __shared__ __align__(16) float smem[kSmemFloats];
    unsigned short* xpkHi = (unsigned short*)(smem + kOffXpkHi);
    unsigned short* xpkLo = (unsigned short*)(smem + kOffXpkLo);
    unsigned short* hpkHi = (unsigned short*)(smem + kOffHpkHi);
    unsigned short* hpkLo = (unsigned short*)(smem + kOffHpkLo);
    float* xg     = smem + kOffXg;
    float* pacc   = smem + kOffPacc;
    float* cinit  = smem + kOffCinit;
    float* biash  = smem + kOffBiash;

    const int tid  = threadIdx.x;
    const int lane = tid & 63;
    const int wv   = tid >> 6;
    const int ln15 = lane & 15;
    const int lh   = lane >> 4;
    const int lay  = blockIdx.x >> 5;        // layer 0..7
    const int chk  = blockIdx.x & 31;        // row chunk 0..31
    const int r0   = chk * kRowsB;
    const int mtA  = 2 * wv, mtB = 2 * wv + 1;  // W-col tiles 0..23
    const bool zr  = (wv < 8);               // tiles 0..15 = z,r gates
    const int grow = tid >> 5;               // gate row (tid<512)
    const int gu0  = (tid & 31) * 4;         // gate unit base

    float* __restrict__ buf    = out;
    float* __restrict__ states = out + (size_t)kB * kT * kU;
    const float* Wh = rec_k + (size_t)lay * kU * kG;
    const float* WxBase = (lay == 0) ? kernel0 : kernels + (size_t)(lay - 1) * kU * kG;
    const int nkf = (lay == 0) ? 1 : 4;

    // zero packed x buffers once (layer 0 relies on k>=8 staying zero)
    for (int j = tid; j < 2 * 4352; j += kThreads) smem[kOffXpkHi + j] = 0.f;

    // ---- W_h -> resident bf16 hi/lo A-fragments (once) ----
    short8 WhiA[4], WloA[4], WhiB[4], WloB[4];
#pragma unroll
    for (int kf = 0; kf < 4; ++kf) {
        float fa[8], fb[8];
#pragma unroll
        for (int e = 0; e < 8; ++e) {
            const int k = kf * 32 + lh * 8 + e;
            fa[e] = Wh[(size_t)k * kG + mtA * 16 + ln15];
            fb[e] = Wh[(size_t)k * kG + mtB * 16 + ln15];
        }
        pack8(fa, WhiA[kf], WloA[kf]);
        pack8(fb, WhiB[kf], WloB[kf]);
    }
    if (tid < kG) {
        const float bx = biases[(size_t)lay * 2 * kG + tid];
        const float bh = biases[(size_t)lay * 2 * kG + kG + tid];
        cinit[tid] = bx + (tid < 2 * kU ? bh : 0.f);  // z,r: bx+bh; cand: bx
        biash[tid] = bh;
    }
    float hr0 = 0.f, hr1 = 0.f, hr2 = 0.f, hr3 = 0.f;
    if (tid < 512) {
        const float* hp = init_h + (size_t)lay * kB * kU + (size_t)(r0 + grow) * kU + gu0;
        hr0 = hp[0]; hr1 = hp[1]; hr2 = hp[2]; hr3 = hp[3];
        unsigned short h0, l0, h1, l1, h2, l2, h3, l3;
        pack1(hr0, h0, l0); pack1(hr1, h1, l1);
        pack1(hr2, h2, l2); pack1(hr3, h3, l3);
        *(unsigned*)&hpkHi[grow * kPk + gu0]     = (unsigned)h0 | ((unsigned)h1 << 16);
        *(unsigned*)&hpkHi[grow * kPk + gu0 + 2] = (unsigned)h2 | ((unsigned)h3 << 16);
        *(unsigned*)&hpkLo[grow * kPk + gu0]     = (unsigned)l0 | ((unsigned)l1 << 16);
        *(unsigned*)&hpkLo[grow * kPk + gu0 + 2] = (unsigned)l2 | ((unsigned)l3 << 16);
    }
    __syncthreads();

#pragma unroll 1
    for (int t0 = 0; t0 < kT; t0 += kW) {
        // ---- acquire x window; pack to bf16 hi/lo during staging ----
        if (lay > 0) {
            if (tid == 0) {
                while ((int)__hip_atomic_load(&flags[(lay - 1) * kChunks + chk],
                                              __ATOMIC_RELAXED,
                                              __HIP_MEMORY_SCOPE_AGENT) < t0 + kW)
                    __builtin_amdgcn_s_sleep(2);
            }
            __syncthreads();
            const unsigned long long* bp = (const unsigned long long*)buf;
            for (int i = tid; i < kW * kRowsB * (kU / 2); i += kThreads) {
                const int t = i >> 10, rr = (i >> 6) & 15, kp = i & 63;
                const unsigned long long v = __hip_atomic_load(
                    &bp[(((size_t)(r0 + rr) * kT + (t0 + t)) * kU) / 2 + kp],
                    __ATOMIC_RELAXED, __HIP_MEMORY_SCOPE_AGENT);
                const float f0 = __uint_as_float((unsigned)v);
                const float f1 = __uint_as_float((unsigned)(v >> 32));
                unsigned short h0, l0, h1, l1;
                pack1(f0, h0, l0); pack1(f1, h1, l1);
                const int row = t * kRowsB + rr;
                *(unsigned*)&xpkHi[row * kPk + 2 * kp] = (unsigned)h0 | ((unsigned)h1 << 16);
                *(unsigned*)&xpkLo[row * kPk + 2 * kp] = (unsigned)l0 | ((unsigned)l1 << 16);
            }
        } else {
            for (int i = tid; i < kW * kRowsB * kF; i += kThreads) {
                const int t = i >> 7, rr = (i >> 3) & 15, k = i & 7;
                const float f = xin[((size_t)(r0 + rr) * kT + (t0 + t)) * kF + k];
                unsigned short h0, l0;
                pack1(f, h0, l0);
                const int row = t * kRowsB + rr;
                xpkHi[row * kPk + k] = h0;
                xpkLo[row * kPk + k] = l0;
            }
        }
        __syncthreads();

        // ---- x-GEMM (window of 4): A=W_x streamed, B=packed x from LDS ----
        f32x4 xDA[kW], xDB[kW];
        {
            const f32x4 cA = *(const f32x4*)&cinit[mtA * 16 + lh * 4];
            const f32x4 cB = *(const f32x4*)&cinit[mtB * 16 + lh * 4];
#pragma unroll
            for (int tt = 0; tt < kW; ++tt) { xDA[tt] = cA; xDB[tt] = cB; }
            const float* Wxp = WxBase;
            asm volatile("" : "+v"(Wxp));  // no LICM hoist across windows
#pragma unroll 1
            for (int kf = 0; kf < nkf; ++kf) {
                float fa[8], fb[8];
#pragma unroll
                for (int e = 0; e < 8; ++e) {
                    const int k = kf * 32 + lh * 8 + e;
                    const bool valid = (lay != 0) || (k < kF);
                    fa[e] = valid ? Wxp[(size_t)k * kG + mtA * 16 + ln15] : 0.f;
                    fb[e] = valid ? Wxp[(size_t)k * kG + mtB * 16 + ln15] : 0.f;
                }
                short8 AhiA, AloA, AhiB, AloB;
                pack8(fa, AhiA, AloA);
                pack8(fb, AhiB, AloB);
#pragma unroll
                for (int tt = 0; tt < kW; ++tt) {
                    const int row = tt * kRowsB + ln15;
                    const short8 Bh = *(const short8*)&xpkHi[row * kPk + kf * 32 + lh * 8];
                    const short8 Bl = *(const short8*)&xpkLo[row * kPk + kf * 32 + lh * 8];
                    xDA[tt] = MFMA(AhiA, Bh, xDA[tt]); xDA[tt] = MFMA(AhiA, Bl, xDA[tt]); xDA[tt] = MFMA(AloA, Bh, xDA[tt]);
                    xDB[tt] = MFMA(AhiB, Bh, xDB[tt]); xDB[tt] = MFMA(AhiB, Bl, xDB[tt]); xDB[tt] = MFMA(AloB, Bh, xDB[tt]);
                }
            }
            if (!zr) {  // cand x-part -> LDS for the gate phase
#pragma unroll
                for (int tt = 0; tt < kW; ++tt) {
                    *(f32x4*)&xg[(tt * 16 + ln15) * 132 + (mtA - 16) * 16 + lh * 4] = xDA[tt];
                    *(f32x4*)&xg[(tt * 16 + ln15) * 132 + (mtB - 16) * 16 + lh * 4] = xDB[tt];
                }
            }
        }

        // ---- kW recurrence steps ----
#pragma unroll
        for (int tt = 0; tt < kW; ++tt) {
            {
                f32x4 DA, DB;
                if (zr) { DA = xDA[tt]; DB = xDB[tt]; }
                else    { f32x4 Z = {0.f, 0.f, 0.f, 0.f}; DA = Z; DB = Z; }
#pragma unroll
                for (int kf = 0; kf < 4; ++kf) {
                    const short8 Bh = *(const short8*)&hpkHi[ln15 * kPk + kf * 32 + lh * 8];
                    const short8 Bl = *(const short8*)&hpkLo[ln15 * kPk + kf * 32 + lh * 8];
                    DA = MFMA(WhiA[kf], Bh, DA); DA = MFMA(WhiA[kf], Bl, DA); DA = MFMA(WloA[kf], Bh, DA);
                    DB = MFMA(WhiB[kf], Bh, DB); DB = MFMA(WhiB[kf], Bl, DB); DB = MFMA(WloB[kf], Bh, DB);
                }
                *(f32x4*)&pacc[ln15 * 388 + mtA * 16 + lh * 4] = DA;
                *(f32x4*)&pacc[ln15 * 388 + mtB * 16 + lh * 4] = DB;
            }
            __syncthreads();

            if (tid < 512) {
                const float* pr = &pacc[grow * 388];
                const f32x4 sz4 = *(const f32x4*)&pr[gu0];
                const f32x4 sr4 = *(const f32x4*)&pr[kU + gu0];
                const f32x4 sh4 = *(const f32x4*)&pr[2 * kU + gu0];
                const f32x4 sx4 = *(const f32x4*)&xg[(tt * 16 + grow) * 132 + gu0];
                const f32x4 bh4 = *(const f32x4*)&biash[2 * kU + gu0];
                const float ho[4] = {hr0, hr1, hr2, hr3};
                float hn[4];
#pragma unroll
                for (int j = 0; j < 4; ++j) {
                    const float z  = frcp(1.f + __expf(-sz4[j]));
                    const float rg = frcp(1.f + __expf(-sr4[j]));
                    const float ta = sx4[j] + rg * (sh4[j] + bh4[j]);
                    const float hh = 1.f - 2.f * frcp(1.f + __expf(2.f * ta));
                    hn[j] = z * ho[j] + (1.f - z) * hh;
                }
                hr0 = hn[0]; hr1 = hn[1]; hr2 = hn[2]; hr3 = hn[3];
                // pack h for next step's MFMA (producer-side, once)
                unsigned short h0, l0, h1, l1, h2, l2, h3, l3;
                pack1(hr0, h0, l0); pack1(hr1, h1, l1);
                pack1(hr2, h2, l2); pack1(hr3, h3, l3);
                *(unsigned*)&hpkHi[grow * kPk + gu0]     = (unsigned)h0 | ((unsigned)h1 << 16);
                *(unsigned*)&hpkHi[grow * kPk + gu0 + 2] = (unsigned)h2 | ((unsigned)h3 << 16);
                *(unsigned*)&hpkLo[grow * kPk + gu0]     = (unsigned)l0 | ((unsigned)l1 << 16);
                *(unsigned*)&hpkLo[grow * kPk + gu0 + 2] = (unsigned)l2 | ((unsigned)l3 << 16);
                // 8-byte atomic write-through to IC (visible to consumer XCDs)
                unsigned long long u01 =
                    (unsigned long long)__float_as_uint(hr0) |
                    ((unsigned long long)__float_as_uint(hr1) << 32);
                unsigned long long u23 =
                    (unsigned long long)__float_as_uint(hr2) |
                    ((unsigned long long)__float_as_uint(hr3) << 32);
                unsigned long long* bp = (unsigned long long*)
                    &buf[((size_t)(r0 + grow) * kT + (t0 + tt)) * kU + gu0];
                __hip_atomic_store(&bp[0], u01, __ATOMIC_RELAXED, __HIP_MEMORY_SCOPE_AGENT);
                __hip_atomic_store(&bp[1], u23, __ATOMIC_RELAXED, __HIP_MEMORY_SCOPE_AGENT);
            }
            __syncthreads();
        }

        // publish window: final __syncthreads drained all stores (vmcnt wait
        // precedes s_barrier), so a RELAXED bump suffices.
        if (tid == 0) {
            __hip_atomic_fetch_add(&flags[lay * kChunks + chk], (unsigned)kW,
                                   __ATOMIC_RELAXED, __HIP_MEMORY_SCOPE_AGENT);
        }
    }

    // ---- final state of this layer ----
    if (tid < 512) {
        float* sp = &states[(size_t)lay * kB * kU + (size_t)(r0 + grow) * kU + gu0];
        sp[0] = hr0; sp[1] = hr1; sp[2] = hr2; sp[3] = hr3;
    }
}

}  // namespace

extern "C" void kernel_launch(void* const* d_in, const int* in_sizes, int n_in,
                              void* d_out, int out_size, void* d_ws, size_t ws_size,
                              hipStream_t stream) {
    const float* xin     = (const float*)d_in[0];
    const float* init_h  = (const float*)d_in[1];
    const float* kernel0 = (const float*)d_in[2];
    const float* kernels = (const float*)d_in[3];
    const float* rec_k   = (const float*)d_in[4];
    const float* biases  = (const float*)d_in[5];
    float* out = (float*)d_out;
    unsigned* flags = (unsigned*)d_ws;

    hipMemsetAsync(d_ws, 0, kL * kChunks * sizeof(unsigned), stream);
    dim3 grid(kL * kChunks);   // 256 blocks = 8 layers x 32 chunks, 1 per CU
    dim3 block(kThreads);      // 768 threads = 12 waves, 3 per SIMD
    gru_all<<<grid, block, 0, stream>>>(xin, init_h, kernel0, kernels, rec_k,
                                        biases, out, flags);
}